// Round 5
// baseline (170.346 us; speedup 1.0000x reference)
//
#include <hip/hip_runtime.h>

// (B,P,C,H,W)=(256,10,32,8,8); Tm=19, Ta=10, hw=64. All I/O fp32.
// Horner: A_0=[F_0;1]; A_{p+1}=A_p*M_p+[F_{p+1};1] (p=0..8) -> A_9=[G;W]
// out[b,t,c,j] = (G[c,:].M_t[:,j]) / (W.M_t[:,j] + eps)
//
// v15: two-kernel split. v12-14 showed the fused kernel pins phase 2 at
// 16 waves/CU behind phase 1's 9 serial barriers, and every intra-kernel
// rescheduling attempt (v13 reg-ring, v14 DMA-ring) lost to the compiler.
//  - k_phase1: v12's proven recursion verbatim (register-staged LDS dbuf,
//    1 barrier/step), writes [G;W] per half-batch to ws (256 x 33 x 64 f32,
//    2.2MB). Identical numerics.
//  - k_phase2: 2560 blocks (one per (b,t)) x 256 thr. 8 blocks/CU = 32
//    waves/CU (full occupancy; launch_bounds(256,8) caps VGPR at 64) -> 8
//    independent waves/SIMD hide the Mt stream latency the fused kernel
//    exposed. G^T staged in 8.5KB LDS (2-way banks = free). k-ascending
//    accumulation -> bit-identical outputs to v12.

#define EPSV 1e-6f

__device__ __forceinline__ float rdlane(float v, int k) {
    return __int_as_float(__builtin_amdgcn_readlane(__float_as_int(v), k));
}

// ---------------- kernel A: recursion -> ws[b][33][64] ----------------
__global__ __launch_bounds__(512, 2) void k_phase1(
    const float* __restrict__ feats,   // (256,10,32,64)
    const float* __restrict__ sim,     // (256,19,64,64)
    float* __restrict__ ws)            // (256,33,64): rows 0..31 G, row 32 W
{
    __shared__ __attribute__((aligned(16))) float Mb[2][4096];  // 32KB dbuf

    const int tid  = threadIdx.x;
    const int lane = tid & 63;
    const int wave = tid >> 6;          // 0..7
    const int b    = blockIdx.x & 255;  // pair (b, b+256) -> same XCD
    const int h    = blockIdx.x >> 8;   // row-half of the batch

    const float* fb = feats + (size_t)b * 20480;   // 10*32*64
    const float* sb = sim   + (size_t)b * 77824;   // 19*64*64

    // stage M_0 into Mb[0]
    {
        const float4 s0 = *(const float4*)&sb[tid * 4];
        const float4 s1 = *(const float4*)&sb[2048 + tid * 4];
        *(float4*)&Mb[0][tid * 4]        = s0;
        *(float4*)&Mb[0][2048 + tid * 4] = s1;
    }

    const int r0 = 16 * h + 2 * wave;
    float a0 = fb[(r0 + 0) * 64 + lane];
    float a1 = fb[(r0 + 1) * 64 + lane];
    float aw = 1.0f;

    __syncthreads();                    // M_0 visible

    for (int p = 0; p < 9; ++p) {
        float4 n0, n1;
        if (p < 8) {                    // 1-ahead prefetch (compiler-proven)
            const float* __restrict__ Mn = sb + (p + 1) * 4096;
            n0 = *(const float4*)&Mn[tid * 4];
            n1 = *(const float4*)&Mn[2048 + tid * 4];
        }
        const float* __restrict__ F = fb + (p + 1) * 2048;
        const float f0 = F[(r0 + 0) * 64 + lane];
        const float f1 = F[(r0 + 1) * 64 + lane];
        const float* __restrict__ Mc = Mb[p & 1];

        float c0 = 0.f, c1 = 0.f, cw = 0.f;
        if (wave == 7) {                // wave-uniform branch
            #pragma unroll
            for (int k = 0; k < 64; ++k) {
                const float m = Mc[k * 64 + lane];   // ds_read_b32, imm offset
                c0 += rdlane(a0, k) * m;
                c1 += rdlane(a1, k) * m;
                cw += rdlane(aw, k) * m;
            }
        } else {
            #pragma unroll
            for (int k = 0; k < 64; ++k) {
                const float m = Mc[k * 64 + lane];
                c0 += rdlane(a0, k) * m;
                c1 += rdlane(a1, k) * m;
            }
        }
        a0 = c0 + f0; a1 = c1 + f1; aw = cw + 1.0f;

        if (p < 8) {
            float* Mw = Mb[(p + 1) & 1];
            *(float4*)&Mw[tid * 4]        = n0;
            *(float4*)&Mw[2048 + tid * 4] = n1;
            __syncthreads();
        }
    }

    // store [G_half; W] rows (coalesced 256B rows)
    float* wb = ws + (size_t)b * 2112;             // 33*64
    wb[(r0 + 0) * 64 + lane] = a0;
    wb[(r0 + 1) * 64 + lane] = a1;
    if (wave == 7 && h == 0) wb[2048 + lane] = aw; // W identical in both halves
}

// ---------------- kernel B: out[b,t] = norm(G_b . M_t) ----------------
__global__ __launch_bounds__(256, 8) void k_phase2(
    const float* __restrict__ sim,     // (256,19,64,64)
    const float* __restrict__ ws,      // (256,33,64)
    float* __restrict__ out)           // (2560,32,64)
{
    __shared__ __attribute__((aligned(16))) float Gts[64 * 34];  // 8.5KB, G^T

    const int tid = threadIdx.x;
    const int bid = blockIdx.x;         // = b*10 + t  (matches out layout)
    const int b   = bid / 10;
    const int t   = bid - b * 10;

    // stage ws[b] transposed: Gts[k*34 + row] (write banks 2-way = free)
    const float* gw = ws + (size_t)b * 2112;
    #pragma unroll
    for (int i = 0; i < 9; ++i) {
        const int idx = i * 256 + tid;
        if (idx < 2112) {
            const int row = idx >> 6, k = idx & 63;
            Gts[k * 34 + row] = gw[idx];
        }
    }
    __syncthreads();

    const int wave = tid >> 6;
    const int lane = tid & 63;
    const int rg   = 8 * wave + ((lane >> 4) << 1);  // even row in 0..30
    const int jj   = (lane & 15) * 4;
    const float* __restrict__ Mt = sim + (size_t)b * 77824 + (size_t)(9 + t) * 4096;

    float acc0 = 0.f, acc1 = 0.f, acc2 = 0.f, acc3 = 0.f;   // row rg
    float acc4 = 0.f, acc5 = 0.f, acc6 = 0.f, acc7 = 0.f;   // row rg+1
    float wv0 = 0.f, wv1 = 0.f, wv2 = 0.f, wv3 = 0.f;

    #pragma unroll 8
    for (int k = 0; k < 64; ++k) {
        const float2 g  = *(const float2*)&Gts[k * 34 + rg];   // rows rg,rg+1
        const float  wk = Gts[k * 34 + 32];                    // W[k] broadcast
        const float4 m  = *(const float4*)&Mt[k * 64 + jj];    // global b128
        wv0  += wk  * m.x; wv1  += wk  * m.y; wv2  += wk  * m.z; wv3  += wk  * m.w;
        acc0 += g.x * m.x; acc1 += g.x * m.y; acc2 += g.x * m.z; acc3 += g.x * m.w;
        acc4 += g.y * m.x; acc5 += g.y * m.y; acc6 += g.y * m.z; acc7 += g.y * m.w;
    }

    const float rwx = 1.f / (wv0 + EPSV), rwy = 1.f / (wv1 + EPSV);
    const float rwz = 1.f / (wv2 + EPSV), rww = 1.f / (wv3 + EPSV);

    float* ob = out + (size_t)bid * 2048;
    float4 o0, o1;
    o0.x = acc0 * rwx; o0.y = acc1 * rwy; o0.z = acc2 * rwz; o0.w = acc3 * rww;
    o1.x = acc4 * rwx; o1.y = acc5 * rwy; o1.z = acc6 * rwz; o1.w = acc7 * rww;
    *(float4*)&ob[(rg + 0) * 64 + jj] = o0;
    *(float4*)&ob[(rg + 1) * 64 + jj] = o1;
}

extern "C" void kernel_launch(void* const* d_in, const int* in_sizes, int n_in,
                              void* d_out, int out_size, void* d_ws, size_t ws_size,
                              hipStream_t stream) {
    const float* feats = (const float*)d_in[0];
    const float* sim   = (const float*)d_in[1];
    float* ws = (float*)d_ws;          // needs 256*33*64*4 = 2.16 MB
    k_phase1<<<512, 512, 0, stream>>>(feats, sim, ws);
    k_phase2<<<2560, 256, 0, stream>>>(sim, ws, (float*)d_out);
}